// Round 3
// baseline (7920.490 us; speedup 1.0000x reference)
//
#include <hip/hip_runtime.h>

#define GRID    256
#define BLOCK   512
#define NWAVES  (BLOCK / 64)
#define CHUNK   5340   // 3*CHUNK*4 = 64080 B LDS (+s_red/s_plane) < 64 KB

// ---------------- coherent workspace access (cross-XCD safe) ----------------
__device__ __forceinline__ float ws_load(const float* p) {
  return __hip_atomic_load(p, __ATOMIC_RELAXED, __HIP_MEMORY_SCOPE_AGENT);
}
__device__ __forceinline__ void ws_store(float* p, float v) {
  __hip_atomic_store(p, v, __ATOMIC_RELAXED, __HIP_MEMORY_SCOPE_AGENT);
}
__device__ __forceinline__ unsigned flag_load_acq(const unsigned* p) {
  return __hip_atomic_load(p, __ATOMIC_ACQUIRE, __HIP_MEMORY_SCOPE_AGENT);
}
__device__ __forceinline__ void flag_store_rel(unsigned* p, unsigned v) {
  __hip_atomic_store(p, v, __ATOMIC_RELEASE, __HIP_MEMORY_SCOPE_AGENT);
}

// ---------------- block reduction: NV values, result in thread 0 ----------------
template <int NV>
__device__ __forceinline__ void block_reduce(float* v, float* sm) {
  #pragma unroll
  for (int off = 32; off > 0; off >>= 1) {
    #pragma unroll
    for (int k = 0; k < NV; ++k) v[k] += __shfl_down(v[k], off, 64);
  }
  const int lane = threadIdx.x & 63;
  const int wid  = threadIdx.x >> 6;
  if (lane == 0) {
    #pragma unroll
    for (int k = 0; k < NV; ++k) sm[wid * NV + k] = v[k];
  }
  __syncthreads();
  if (threadIdx.x == 0) {
    #pragma unroll
    for (int w = 1; w < NWAVES; ++w) {
      #pragma unroll
      for (int k = 0; k < NV; ++k) v[k] += sm[w * NV + k];
    }
  }
  __syncthreads();
}

// ---------------- 3x3 helpers (row-major float[9]) ----------------
__device__ __forceinline__ void mat3_mul(const float* A, const float* B, float* C) {
  #pragma unroll
  for (int i = 0; i < 3; ++i)
    #pragma unroll
    for (int j = 0; j < 3; ++j)
      C[i*3+j] = A[i*3+0]*B[0*3+j] + A[i*3+1]*B[1*3+j] + A[i*3+2]*B[2*3+j];
}
__device__ __forceinline__ void mat3_mul_bt(const float* A, const float* B, float* C) {
  // C = A * B^T
  #pragma unroll
  for (int i = 0; i < 3; ++i)
    #pragma unroll
    for (int j = 0; j < 3; ++j)
      C[i*3+j] = A[i*3+0]*B[j*3+0] + A[i*3+1]*B[j*3+1] + A[i*3+2]*B[j*3+2];
}
__device__ __forceinline__ void mat3_inv(const float* m, float* inv) {
  float A =  (m[4]*m[8] - m[5]*m[7]);
  float B = -(m[3]*m[8] - m[5]*m[6]);
  float C =  (m[3]*m[7] - m[4]*m[6]);
  float det = m[0]*A + m[1]*B + m[2]*C;
  float id = 1.0f / det;
  inv[0] = A * id;
  inv[1] = -(m[1]*m[8] - m[2]*m[7]) * id;
  inv[2] =  (m[1]*m[5] - m[2]*m[4]) * id;
  inv[3] = B * id;
  inv[4] =  (m[0]*m[8] - m[2]*m[6]) * id;
  inv[5] = -(m[0]*m[5] - m[2]*m[3]) * id;
  inv[6] = C * id;
  inv[7] = -(m[0]*m[7] - m[1]*m[6]) * id;
  inv[8] =  (m[0]*m[4] - m[1]*m[3]) * id;
}

__global__ __launch_bounds__(BLOCK)
void sim_kernel(const float* __restrict__ xg,
                const float* __restrict__ mc_p,
                const float* __restrict__ itr_p,
                const float* __restrict__ iq_p,
                const float* __restrict__ iv_p,
                const float* __restrict__ kn_p,
                const float* __restrict__ mu_p,
                const float* __restrict__ ldp_p,
                const float* __restrict__ adp_p,
                float* __restrict__ out,
                float* __restrict__ ws,
                int N, int T)
{
  const int tid = threadIdx.x;
  const int bid = blockIdx.x;
  const int gtid = bid * BLOCK + tid;
  const int gthreads = GRID * BLOCK;

  __shared__ __align__(16) float sXx[CHUNK];
  __shared__ __align__(16) float sXy[CHUNK];
  __shared__ __align__(16) float sXz[CHUNK];
  __shared__ float s_red[NWAVES * 8];
  __shared__ float s_plane[8];

  // fp32 constants exactly as the fp32 reference sees them
  const float nx  = (float)(-0.3420201433256687);   // -sin(20deg)
  const float ny  = (float)( 0.9396926207859084);   //  cos(20deg)
  const float DTF = (float)(1.0 / 60.0 / 10.0);
  const float HDT = (float)(0.5 * (1.0 / 60.0 / 10.0));
  const float DTH = (float)(-0.9396926207859084 * 0.1); // -COS_S*INIT_HEIGHT
  const float GYDT = -9.8f * (float)(1.0 / 60.0 / 10.0);

  const float mc0 = mc_p[0], mc1 = mc_p[1], mc2 = mc_p[2];

  // workspace: per-block 32B records. [0..3]=payload, word4 = flag (as uint).
  // Poison 0xAAAAAAAA never equals any wanted flag (1..241, 0xC0FFEE).
  float* buf0 = ws;                  // GRID*8 floats
  float* buf1 = ws + GRID * 8;       // GRID*8
  float* bufI = ws + 2 * GRID * 8;   // GRID*8 : [0..5]=inertia, word6=flag

  // ---- stage part of x into LDS (SoA) ----
  const int vstart = bid * CHUNK;
  int cl = N - vstart; if (cl > CHUNK) cl = CHUNK; if (cl < 0) cl = 0;
  for (int i = tid; i < cl; i += BLOCK) {
    const float* p = xg + (size_t)(vstart + i) * 3;
    sXx[i] = p[0]; sXy[i] = p[1]; sXz[i] = p[2];
  }
  __syncthreads();

  const int tailbase = GRID * CHUNK;   // verts beyond LDS capacity, stay in per-XCD L2

  // ---- inertia: S[i][j] = sum r_i r_j ----
  {
    float v6[6] = {0,0,0,0,0,0};
    for (int i = tid; i < cl; i += BLOCK) {
      float r0 = sXx[i] - mc0, r1 = sXy[i] - mc1, r2 = sXz[i] - mc2;
      v6[0] += r0*r0; v6[1] += r1*r1; v6[2] += r2*r2;
      v6[3] += r0*r1; v6[4] += r0*r2; v6[5] += r1*r2;
    }
    for (int i = tailbase + gtid; i < N; i += gthreads) {
      const float* p = xg + (size_t)i * 3;
      float r0 = p[0] - mc0, r1 = p[1] - mc1, r2 = p[2] - mc2;
      v6[0] += r0*r0; v6[1] += r1*r1; v6[2] += r2*r2;
      v6[3] += r0*r1; v6[4] += r0*r2; v6[5] += r1*r2;
    }
    block_reduce<6>(v6, s_red);
    if (tid == 0) {
      #pragma unroll
      for (int k = 0; k < 6; ++k) ws_store(&bufI[bid * 8 + k], v6[k]);
      flag_store_rel((unsigned*)&bufI[bid * 8 + 6], 0xC0FFEEu);
    }
  }

  // all-to-all gather of inertia partials (no grid.sync)
  float In[9];
  {
    float v6[6] = {0,0,0,0,0,0};
    if (tid < GRID) {
      const unsigned* fp = (const unsigned*)&bufI[tid * 8 + 6];
      while (flag_load_acq(fp) != 0xC0FFEEu) __builtin_amdgcn_s_sleep(1);
      #pragma unroll
      for (int k = 0; k < 6; ++k) v6[k] = ws_load(&bufI[tid * 8 + k]);
    }
    block_reduce<6>(v6, s_red);
    // only thread 0's values are meaningful below
    float trc = v6[0] + v6[1] + v6[2];
    In[0] = trc - v6[0]; In[4] = trc - v6[1]; In[8] = trc - v6[2];
    In[1] = -v6[3]; In[3] = -v6[3];
    In[2] = -v6[4]; In[6] = -v6[4];
    In[5] = -v6[5]; In[7] = -v6[5];
  }

  // ---- initial state (thread-0-owned) ----
  float tr0 = itr_p[0], tr1 = itr_p[1], tr2 = itr_p[2];
  float q0 = iq_p[0], q1 = iq_p[1], q2 = iq_p[2], q3 = iq_p[3];
  {
    float n0 = sqrtf(q0*q0 + q1*q1 + q2*q2 + q3*q3);
    q0 /= n0; q1 /= n0; q2 /= n0; q3 /= n0;
  }
  float v0 = iv_p[0], v1 = iv_p[1], v2 = iv_p[2];
  float om0 = 0.f, om1 = 0.f, om2 = 0.f;
  const float knv = kn_p[0], muv = mu_p[0], ldv = ldp_p[0], adv = adp_p[0];
  const float inv_mass = 1.0f / (float)N;

  float Rm[9];

  for (int t = 0; t < T; ++t) {
    // ---- plane parameters from current state (thread 0) ----
    if (tid == 0) {
      float qn = sqrtf(q0*q0 + q1*q1 + q2*q2 + q3*q3);
      float w = q0/qn, xq = q1/qn, yq = q2/qn, zq = q3/qn;
      Rm[0] = 1.f - 2.f*yq*yq - 2.f*zq*zq; Rm[1] = 2.f*xq*yq - 2.f*w*zq; Rm[2] = 2.f*xq*zq + 2.f*w*yq;
      Rm[3] = 2.f*xq*yq + 2.f*w*zq; Rm[4] = 1.f - 2.f*xq*xq - 2.f*zq*zq; Rm[5] = 2.f*yq*zq - 2.f*w*xq;
      Rm[6] = 2.f*xq*zq - 2.f*w*yq; Rm[7] = 2.f*yq*zq + 2.f*w*xq; Rm[8] = 1.f - 2.f*xq*xq - 2.f*yq*yq;
      // a = R^T n
      float a0 = Rm[0]*nx + Rm[3]*ny;
      float a1 = Rm[1]*nx + Rm[4]*ny;
      float a2 = Rm[2]*nx + Rm[5]*ny;
      // w_ = n x omega ; b = R^T w_
      float w0 = ny*om2, w1 = -nx*om2, w2 = nx*om1 - ny*om0;
      float b0 = Rm[0]*w0 + Rm[3]*w1 + Rm[6]*w2;
      float b1 = Rm[1]*w0 + Rm[4]*w1 + Rm[7]*w2;
      float b2 = Rm[2]*w0 + Rm[5]*w1 + Rm[8]*w2;
      float ca = DTH - ((tr0 + mc0)*nx + (tr1 + mc1)*ny);
      float cb = -(v0*nx + v1*ny);
      s_plane[0] = a0; s_plane[1] = a1; s_plane[2] = a2;
      s_plane[3] = b0; s_plane[4] = b1; s_plane[5] = b2;
      s_plane[6] = ca; s_plane[7] = cb;
    }
    __syncthreads();
    const float a0 = s_plane[0], a1 = s_plane[1], a2 = s_plane[2];
    const float b0 = s_plane[3], b1 = s_plane[4], b2 = s_plane[5];
    const float ca = s_plane[6], cb = s_plane[7];

    // ---- masked reduction: LDS chunk + L2-resident tail ----
    float acc[4] = {0.f, 0.f, 0.f, 0.f};
    for (int i = tid; i < cl; i += BLOCK) {
      float x0 = sXx[i], x1 = sXy[i], x2 = sXz[i];
      float da = x0*a0 + x1*a1 + x2*a2;
      float db = x0*b0 + x1*b1 + x2*b2;
      if (da < ca && db < cb) { acc[0] += 1.f; acc[1] += x0; acc[2] += x1; acc[3] += x2; }
    }
    for (int i = tailbase + gtid; i < N; i += gthreads) {
      const float* p = xg + (size_t)i * 3;
      float x0 = p[0], x1 = p[1], x2 = p[2];
      float da = x0*a0 + x1*a1 + x2*a2;
      float db = x0*b0 + x1*b1 + x2*b2;
      if (da < ca && db < cb) { acc[0] += 1.f; acc[1] += x0; acc[2] += x1; acc[3] += x2; }
    }
    block_reduce<4>(acc, s_red);

    // ---- publish partial: payload (relaxed) then flag = t+1 (release) ----
    float* pb = (t & 1) ? buf1 : buf0;   // buffer reuse at distance 2 is WAR-safe:
                                         // writing step t needs all partials of t-1,
                                         // which needs every block done reading t-2.
    if (tid == 0) {
      #pragma unroll
      for (int k = 0; k < 4; ++k) ws_store(&pb[bid * 8 + k], acc[k]);
      flag_store_rel((unsigned*)&pb[bid * 8 + 4], (unsigned)(t + 1));
    }

    // ---- all-to-all gather: thread j polls block j's record (no RMW, no counter) ----
    float tot[4] = {0.f, 0.f, 0.f, 0.f};
    if (tid < GRID) {
      const unsigned* fp = (const unsigned*)&pb[tid * 8 + 4];
      while (flag_load_acq(fp) != (unsigned)(t + 1)) __builtin_amdgcn_s_sleep(1);
      #pragma unroll
      for (int k = 0; k < 4; ++k) tot[k] = ws_load(&pb[tid * 8 + k]);
    }
    block_reduce<4>(tot, s_red);

    // ---- serial physics update (thread 0 of every block, bit-identical) ----
    if (tid == 0) {
      float num = tot[0];
      float numf = fmaxf(num, 1.0f);
      float ri0 = tot[1] / numf, ri1 = tot[2] / numf, ri2 = tot[3] / numf;
      float Ri0 = Rm[0]*ri0 + Rm[1]*ri1 + Rm[2]*ri2;
      float Ri1 = Rm[3]*ri0 + Rm[4]*ri1 + Rm[5]*ri2;
      float Ri2 = Rm[6]*ri0 + Rm[7]*ri1 + Rm[8]*ri2;
      float dv0 = 0.f, dv1 = 0.f, dv2 = 0.f, dm0 = 0.f, dm1 = 0.f, dm2 = 0.f;
      if (num > 0.0f) {
        float vi0 = v0 + om1*Ri2 - om2*Ri1;
        float vi1 = v1 + om2*Ri0 - om0*Ri2;
        float vi2 = v2 + om0*Ri1 - om1*Ri0;
        float vdn = vi0*nx + vi1*ny;
        float vn0 = vdn*nx, vn1 = vdn*ny;           // vn2 == 0 exactly
        float vt0 = vi0 - vn0, vt1 = vi1 - vn1, vt2 = vi2;
        float nvn = sqrtf(vn0*vn0 + vn1*vn1);
        float nvt = sqrtf(vt0*vt0 + vt1*vt1 + vt2*vt2);
        float alpha = fmaxf(1.0f - muv*(1.0f + knv)*(nvn/(nvt + 1e-6f)), 0.0f);
        float dvi0 = (-knv*vn0 + alpha*vt0) - vi0;
        float dvi1 = (-knv*vn1 + alpha*vt1) - vi1;
        float dvi2 = (alpha*vt2) - vi2;
        float Tm[9]; mat3_mul(Rm, In, Tm);
        float Iw[9]; mat3_mul_bt(Tm, Rm, Iw);       // I = R * inertia * R^T
        float Ii[9]; mat3_inv(Iw, Ii);
        float Cx[9] = {0.f, -Ri2, Ri1,  Ri2, 0.f, -Ri0,  -Ri1, Ri0, 0.f};
        float T2[9]; mat3_mul(Cx, Ii, T2);
        float T3[9]; mat3_mul(T2, Cx, T3);
        float K[9];
        #pragma unroll
        for (int k = 0; k < 9; ++k) K[k] = -T3[k];
        K[0] += inv_mass; K[4] += inv_mass; K[8] += inv_mass;
        float Ki[9]; mat3_inv(K, Ki);
        float J0 = Ki[0]*dvi0 + Ki[1]*dvi1 + Ki[2]*dvi2;
        float J1 = Ki[3]*dvi0 + Ki[4]*dvi1 + Ki[5]*dvi2;
        float J2 = Ki[6]*dvi0 + Ki[7]*dvi1 + Ki[8]*dvi2;
        dv0 = J0*inv_mass; dv1 = J1*inv_mass; dv2 = J2*inv_mass;
        float c0 = -Ri2*J1 + Ri1*J2;
        float c1 =  Ri2*J0 - Ri0*J2;
        float c2 = -Ri1*J0 + Ri0*J1;
        dm0 = Ii[0]*c0 + Ii[1]*c1 + Ii[2]*c2;
        dm1 = Ii[3]*c0 + Ii[4]*c1 + Ii[5]*c2;
        dm2 = Ii[6]*c0 + Ii[7]*c1 + Ii[8]*c2;
      }
      v0 = v0*ldv + dv0;
      v1 = (v1 + GYDT)*ldv + dv1;
      v2 = v2*ldv + dv2;
      om0 = om0*adv + dm0; om1 = om1*adv + dm1; om2 = om2*adv + dm2;
      tr0 = tr0 + DTF*v0; tr1 = tr1 + DTF*v1; tr2 = tr2 + DTF*v2;
      float wx = om0*HDT, wy = om1*HDT, wz = om2*HDT;
      float dq0 = -wx*q1 - wy*q2 - wz*q3;
      float dq1 =  wx*q0 + wy*q3 - wz*q2;
      float dq2 =  wy*q0 + wz*q1 - wx*q3;
      float dq3 =  wz*q0 + wx*q2 - wy*q1;
      q0 += dq0; q1 += dq1; q2 += dq2; q3 += dq3;
      float qn2 = sqrtf(q0*q0 + q1*q1 + q2*q2 + q3*q3);
      q0 /= qn2; q1 /= qn2; q2 /= qn2; q3 /= qn2;
      if (bid == 0) {
        float* o = out + (size_t)t * 7;
        o[0] = tr0; o[1] = tr1; o[2] = tr2;
        o[3] = q0;  o[4] = q1;  o[5] = q2;  o[6] = q3;
      }
    }
  }
}

extern "C" void kernel_launch(void* const* d_in, const int* in_sizes, int n_in,
                              void* d_out, int out_size, void* d_ws, size_t ws_size,
                              hipStream_t stream) {
  const float* x   = (const float*)d_in[0];
  const float* mc  = (const float*)d_in[1];
  const float* itr = (const float*)d_in[2];
  const float* iq  = (const float*)d_in[3];
  const float* iv  = (const float*)d_in[4];
  const float* kn  = (const float*)d_in[5];
  const float* mu  = (const float*)d_in[6];
  const float* ldp = (const float*)d_in[7];
  const float* adp = (const float*)d_in[8];
  float* out = (float*)d_out;
  float* ws  = (float*)d_ws;
  int N = in_sizes[0] / 3;
  int T = out_size / 7;

  void* args[] = {(void*)&x, (void*)&mc, (void*)&itr, (void*)&iq, (void*)&iv,
                  (void*)&kn, (void*)&mu, (void*)&ldp, (void*)&adp,
                  (void*)&out, (void*)&ws, (void*)&N, (void*)&T};
  // cooperative launch kept ONLY for the co-residency guarantee (no grid.sync inside)
  hipLaunchCooperativeKernel((void*)sim_kernel, dim3(GRID), dim3(BLOCK),
                             args, 0, stream);
}

// Round 4
// 3046.955 us; speedup vs baseline: 2.5995x; 2.5995x over previous
//
#include <hip/hip_runtime.h>

#define GRID    256
#define BLOCK   512
#define NWAVES  (BLOCK / 64)
#define CHUNK   5340   // 3*CHUNK*4 = 64080 B LDS (+s_red/s_plane) < 64 KB

// ---------------- coherent workspace access (cross-XCD safe) ----------------
// Agent-scope RELAXED atomics on gfx950 compile to global_load/store with
// sc0 sc1 (bypass L1/L2, hit the coherence point) and NO bulk cache
// invalidate. Acquire loads additionally emit buffer_inv (whole-L2 invalidate)
// -- round 3 showed per-poll acquire costs ~5 us/step + evicts the L2 tail.
__device__ __forceinline__ float ws_load(const float* p) {
  return __hip_atomic_load(p, __ATOMIC_RELAXED, __HIP_MEMORY_SCOPE_AGENT);
}
__device__ __forceinline__ void ws_store(float* p, float v) {
  __hip_atomic_store(p, v, __ATOMIC_RELAXED, __HIP_MEMORY_SCOPE_AGENT);
}
__device__ __forceinline__ unsigned flag_load_rlx(const unsigned* p) {
  return __hip_atomic_load(p, __ATOMIC_RELAXED, __HIP_MEMORY_SCOPE_AGENT);
}
__device__ __forceinline__ unsigned flag_load_acq(const unsigned* p) {
  return __hip_atomic_load(p, __ATOMIC_ACQUIRE, __HIP_MEMORY_SCOPE_AGENT);
}
__device__ __forceinline__ void flag_store_rel(unsigned* p, unsigned v) {
  __hip_atomic_store(p, v, __ATOMIC_RELEASE, __HIP_MEMORY_SCOPE_AGENT);
}

// Poll: relaxed fast path (no invalidates); rare acquire fallback guarantees
// progress even if a relaxed read could ever be served stale.
__device__ __forceinline__ void poll_flag(const unsigned* fp, unsigned want) {
  int it = 0;
  for (;;) {
    if (flag_load_rlx(fp) == want) return;
    if ((++it & 63) == 0) {
      if (flag_load_acq(fp) == want) return;
    }
    __builtin_amdgcn_s_sleep(1);
  }
}

// ---------------- block reduction: NV values, result in thread 0 ----------------
template <int NV>
__device__ __forceinline__ void block_reduce(float* v, float* sm) {
  #pragma unroll
  for (int off = 32; off > 0; off >>= 1) {
    #pragma unroll
    for (int k = 0; k < NV; ++k) v[k] += __shfl_down(v[k], off, 64);
  }
  const int lane = threadIdx.x & 63;
  const int wid  = threadIdx.x >> 6;
  if (lane == 0) {
    #pragma unroll
    for (int k = 0; k < NV; ++k) sm[wid * NV + k] = v[k];
  }
  __syncthreads();
  if (threadIdx.x == 0) {
    #pragma unroll
    for (int w = 1; w < NWAVES; ++w) {
      #pragma unroll
      for (int k = 0; k < NV; ++k) v[k] += sm[w * NV + k];
    }
  }
  __syncthreads();
}

// ---------------- 3x3 helpers (row-major float[9]) ----------------
__device__ __forceinline__ void mat3_mul(const float* A, const float* B, float* C) {
  #pragma unroll
  for (int i = 0; i < 3; ++i)
    #pragma unroll
    for (int j = 0; j < 3; ++j)
      C[i*3+j] = A[i*3+0]*B[0*3+j] + A[i*3+1]*B[1*3+j] + A[i*3+2]*B[2*3+j];
}
__device__ __forceinline__ void mat3_mul_bt(const float* A, const float* B, float* C) {
  // C = A * B^T
  #pragma unroll
  for (int i = 0; i < 3; ++i)
    #pragma unroll
    for (int j = 0; j < 3; ++j)
      C[i*3+j] = A[i*3+0]*B[j*3+0] + A[i*3+1]*B[j*3+1] + A[i*3+2]*B[j*3+2];
}
__device__ __forceinline__ void mat3_inv(const float* m, float* inv) {
  float A =  (m[4]*m[8] - m[5]*m[7]);
  float B = -(m[3]*m[8] - m[5]*m[6]);
  float C =  (m[3]*m[7] - m[4]*m[6]);
  float det = m[0]*A + m[1]*B + m[2]*C;
  float id = 1.0f / det;
  inv[0] = A * id;
  inv[1] = -(m[1]*m[8] - m[2]*m[7]) * id;
  inv[2] =  (m[1]*m[5] - m[2]*m[4]) * id;
  inv[3] = B * id;
  inv[4] =  (m[0]*m[8] - m[2]*m[6]) * id;
  inv[5] = -(m[0]*m[5] - m[2]*m[3]) * id;
  inv[6] = C * id;
  inv[7] = -(m[0]*m[7] - m[1]*m[6]) * id;
  inv[8] =  (m[0]*m[4] - m[1]*m[3]) * id;
}

__global__ __launch_bounds__(BLOCK)
void sim_kernel(const float* __restrict__ xg,
                const float* __restrict__ mc_p,
                const float* __restrict__ itr_p,
                const float* __restrict__ iq_p,
                const float* __restrict__ iv_p,
                const float* __restrict__ kn_p,
                const float* __restrict__ mu_p,
                const float* __restrict__ ldp_p,
                const float* __restrict__ adp_p,
                float* __restrict__ out,
                float* __restrict__ ws,
                int N, int T)
{
  const int tid = threadIdx.x;
  const int bid = blockIdx.x;
  const int gtid = bid * BLOCK + tid;
  const int gthreads = GRID * BLOCK;

  __shared__ __align__(16) float sXx[CHUNK];
  __shared__ __align__(16) float sXy[CHUNK];
  __shared__ __align__(16) float sXz[CHUNK];
  __shared__ float s_red[NWAVES * 8];
  __shared__ float s_plane[8];

  // fp32 constants exactly as the fp32 reference sees them
  const float nx  = (float)(-0.3420201433256687);   // -sin(20deg)
  const float ny  = (float)( 0.9396926207859084);   //  cos(20deg)
  const float DTF = (float)(1.0 / 60.0 / 10.0);
  const float HDT = (float)(0.5 * (1.0 / 60.0 / 10.0));
  const float DTH = (float)(-0.9396926207859084 * 0.1); // -COS_S*INIT_HEIGHT
  const float GYDT = -9.8f * (float)(1.0 / 60.0 / 10.0);

  const float mc0 = mc_p[0], mc1 = mc_p[1], mc2 = mc_p[2];

  // workspace: per-block 32B records. [0..3]=payload, word4 = flag (as uint).
  // Poison 0xAAAAAAAA never equals any wanted flag (1..241, 0xC0FFEE).
  float* buf0 = ws;                  // GRID*8 floats
  float* buf1 = ws + GRID * 8;       // GRID*8
  float* bufI = ws + 2 * GRID * 8;   // GRID*8 : [0..5]=inertia, word6=flag

  // ---- stage part of x into LDS (SoA) ----
  const int vstart = bid * CHUNK;
  int cl = N - vstart; if (cl > CHUNK) cl = CHUNK; if (cl < 0) cl = 0;
  for (int i = tid; i < cl; i += BLOCK) {
    const float* p = xg + (size_t)(vstart + i) * 3;
    sXx[i] = p[0]; sXy[i] = p[1]; sXz[i] = p[2];
  }
  __syncthreads();

  const int tailbase = GRID * CHUNK;   // verts beyond LDS capacity, stay in per-XCD L2

  // ---- inertia: S[i][j] = sum r_i r_j ----
  {
    float v6[6] = {0,0,0,0,0,0};
    for (int i = tid; i < cl; i += BLOCK) {
      float r0 = sXx[i] - mc0, r1 = sXy[i] - mc1, r2 = sXz[i] - mc2;
      v6[0] += r0*r0; v6[1] += r1*r1; v6[2] += r2*r2;
      v6[3] += r0*r1; v6[4] += r0*r2; v6[5] += r1*r2;
    }
    for (int i = tailbase + gtid; i < N; i += gthreads) {
      const float* p = xg + (size_t)i * 3;
      float r0 = p[0] - mc0, r1 = p[1] - mc1, r2 = p[2] - mc2;
      v6[0] += r0*r0; v6[1] += r1*r1; v6[2] += r2*r2;
      v6[3] += r0*r1; v6[4] += r0*r2; v6[5] += r1*r2;
    }
    block_reduce<6>(v6, s_red);
    if (tid == 0) {
      #pragma unroll
      for (int k = 0; k < 6; ++k) ws_store(&bufI[bid * 8 + k], v6[k]);
      flag_store_rel((unsigned*)&bufI[bid * 8 + 6], 0xC0FFEEu);
    }
  }

  // all-to-all gather of inertia partials (relaxed polls, no grid.sync)
  float In[9];
  {
    float v6[6] = {0,0,0,0,0,0};
    if (tid < GRID) {
      poll_flag((const unsigned*)&bufI[tid * 8 + 6], 0xC0FFEEu);
      #pragma unroll
      for (int k = 0; k < 6; ++k) v6[k] = ws_load(&bufI[tid * 8 + k]);
    }
    block_reduce<6>(v6, s_red);
    // only thread 0's values are meaningful below
    float trc = v6[0] + v6[1] + v6[2];
    In[0] = trc - v6[0]; In[4] = trc - v6[1]; In[8] = trc - v6[2];
    In[1] = -v6[3]; In[3] = -v6[3];
    In[2] = -v6[4]; In[6] = -v6[4];
    In[5] = -v6[5]; In[7] = -v6[5];
  }

  // ---- initial state (thread-0-owned) ----
  float tr0 = itr_p[0], tr1 = itr_p[1], tr2 = itr_p[2];
  float q0 = iq_p[0], q1 = iq_p[1], q2 = iq_p[2], q3 = iq_p[3];
  {
    float n0 = sqrtf(q0*q0 + q1*q1 + q2*q2 + q3*q3);
    q0 /= n0; q1 /= n0; q2 /= n0; q3 /= n0;
  }
  float v0 = iv_p[0], v1 = iv_p[1], v2 = iv_p[2];
  float om0 = 0.f, om1 = 0.f, om2 = 0.f;
  const float knv = kn_p[0], muv = mu_p[0], ldv = ldp_p[0], adv = adp_p[0];
  const float inv_mass = 1.0f / (float)N;

  float Rm[9];

  for (int t = 0; t < T; ++t) {
    // ---- plane parameters from current state (thread 0) ----
    if (tid == 0) {
      float qn = sqrtf(q0*q0 + q1*q1 + q2*q2 + q3*q3);
      float w = q0/qn, xq = q1/qn, yq = q2/qn, zq = q3/qn;
      Rm[0] = 1.f - 2.f*yq*yq - 2.f*zq*zq; Rm[1] = 2.f*xq*yq - 2.f*w*zq; Rm[2] = 2.f*xq*zq + 2.f*w*yq;
      Rm[3] = 2.f*xq*yq + 2.f*w*zq; Rm[4] = 1.f - 2.f*xq*xq - 2.f*zq*zq; Rm[5] = 2.f*yq*zq - 2.f*w*xq;
      Rm[6] = 2.f*xq*zq - 2.f*w*yq; Rm[7] = 2.f*yq*zq + 2.f*w*xq; Rm[8] = 1.f - 2.f*xq*xq - 2.f*yq*yq;
      // a = R^T n
      float a0 = Rm[0]*nx + Rm[3]*ny;
      float a1 = Rm[1]*nx + Rm[4]*ny;
      float a2 = Rm[2]*nx + Rm[5]*ny;
      // w_ = n x omega ; b = R^T w_
      float w0 = ny*om2, w1 = -nx*om2, w2 = nx*om1 - ny*om0;
      float b0 = Rm[0]*w0 + Rm[3]*w1 + Rm[6]*w2;
      float b1 = Rm[1]*w0 + Rm[4]*w1 + Rm[7]*w2;
      float b2 = Rm[2]*w0 + Rm[5]*w1 + Rm[8]*w2;
      float ca = DTH - ((tr0 + mc0)*nx + (tr1 + mc1)*ny);
      float cb = -(v0*nx + v1*ny);
      s_plane[0] = a0; s_plane[1] = a1; s_plane[2] = a2;
      s_plane[3] = b0; s_plane[4] = b1; s_plane[5] = b2;
      s_plane[6] = ca; s_plane[7] = cb;
    }
    __syncthreads();
    const float a0 = s_plane[0], a1 = s_plane[1], a2 = s_plane[2];
    const float b0 = s_plane[3], b1 = s_plane[4], b2 = s_plane[5];
    const float ca = s_plane[6], cb = s_plane[7];

    // ---- masked reduction: LDS chunk + L2-resident tail ----
    float acc[4] = {0.f, 0.f, 0.f, 0.f};
    for (int i = tid; i < cl; i += BLOCK) {
      float x0 = sXx[i], x1 = sXy[i], x2 = sXz[i];
      float da = x0*a0 + x1*a1 + x2*a2;
      float db = x0*b0 + x1*b1 + x2*b2;
      if (da < ca && db < cb) { acc[0] += 1.f; acc[1] += x0; acc[2] += x1; acc[3] += x2; }
    }
    for (int i = tailbase + gtid; i < N; i += gthreads) {
      const float* p = xg + (size_t)i * 3;
      float x0 = p[0], x1 = p[1], x2 = p[2];
      float da = x0*a0 + x1*a1 + x2*a2;
      float db = x0*b0 + x1*b1 + x2*b2;
      if (da < ca && db < cb) { acc[0] += 1.f; acc[1] += x0; acc[2] += x1; acc[3] += x2; }
    }
    block_reduce<4>(acc, s_red);

    // ---- publish partial: payload (relaxed sc1) then flag = t+1 (release) ----
    float* pb = (t & 1) ? buf1 : buf0;   // buffer reuse at distance 2 is WAR-safe:
                                         // writing step t needs all partials of t-1,
                                         // which needs every block done reading t-2.
    if (tid == 0) {
      #pragma unroll
      for (int k = 0; k < 4; ++k) ws_store(&pb[bid * 8 + k], acc[k]);
      flag_store_rel((unsigned*)&pb[bid * 8 + 4], (unsigned)(t + 1));
    }

    // ---- all-to-all gather: thread j polls block j's record (relaxed, no inv) ----
    float tot[4] = {0.f, 0.f, 0.f, 0.f};
    if (tid < GRID) {
      poll_flag((const unsigned*)&pb[tid * 8 + 4], (unsigned)(t + 1));
      #pragma unroll
      for (int k = 0; k < 4; ++k) tot[k] = ws_load(&pb[tid * 8 + k]);
    }
    block_reduce<4>(tot, s_red);

    // ---- serial physics update (thread 0 of every block, bit-identical) ----
    if (tid == 0) {
      float num = tot[0];
      float numf = fmaxf(num, 1.0f);
      float ri0 = tot[1] / numf, ri1 = tot[2] / numf, ri2 = tot[3] / numf;
      float Ri0 = Rm[0]*ri0 + Rm[1]*ri1 + Rm[2]*ri2;
      float Ri1 = Rm[3]*ri0 + Rm[4]*ri1 + Rm[5]*ri2;
      float Ri2 = Rm[6]*ri0 + Rm[7]*ri1 + Rm[8]*ri2;
      float dv0 = 0.f, dv1 = 0.f, dv2 = 0.f, dm0 = 0.f, dm1 = 0.f, dm2 = 0.f;
      if (num > 0.0f) {
        float vi0 = v0 + om1*Ri2 - om2*Ri1;
        float vi1 = v1 + om2*Ri0 - om0*Ri2;
        float vi2 = v2 + om0*Ri1 - om1*Ri0;
        float vdn = vi0*nx + vi1*ny;
        float vn0 = vdn*nx, vn1 = vdn*ny;           // vn2 == 0 exactly
        float vt0 = vi0 - vn0, vt1 = vi1 - vn1, vt2 = vi2;
        float nvn = sqrtf(vn0*vn0 + vn1*vn1);
        float nvt = sqrtf(vt0*vt0 + vt1*vt1 + vt2*vt2);
        float alpha = fmaxf(1.0f - muv*(1.0f + knv)*(nvn/(nvt + 1e-6f)), 0.0f);
        float dvi0 = (-knv*vn0 + alpha*vt0) - vi0;
        float dvi1 = (-knv*vn1 + alpha*vt1) - vi1;
        float dvi2 = (alpha*vt2) - vi2;
        float Tm[9]; mat3_mul(Rm, In, Tm);
        float Iw[9]; mat3_mul_bt(Tm, Rm, Iw);       // I = R * inertia * R^T
        float Ii[9]; mat3_inv(Iw, Ii);
        float Cx[9] = {0.f, -Ri2, Ri1,  Ri2, 0.f, -Ri0,  -Ri1, Ri0, 0.f};
        float T2[9]; mat3_mul(Cx, Ii, T2);
        float T3[9]; mat3_mul(T2, Cx, T3);
        float K[9];
        #pragma unroll
        for (int k = 0; k < 9; ++k) K[k] = -T3[k];
        K[0] += inv_mass; K[4] += inv_mass; K[8] += inv_mass;
        float Ki[9]; mat3_inv(K, Ki);
        float J0 = Ki[0]*dvi0 + Ki[1]*dvi1 + Ki[2]*dvi2;
        float J1 = Ki[3]*dvi0 + Ki[4]*dvi1 + Ki[5]*dvi2;
        float J2 = Ki[6]*dvi0 + Ki[7]*dvi1 + Ki[8]*dvi2;
        dv0 = J0*inv_mass; dv1 = J1*inv_mass; dv2 = J2*inv_mass;
        float c0 = -Ri2*J1 + Ri1*J2;
        float c1 =  Ri2*J0 - Ri0*J2;
        float c2 = -Ri1*J0 + Ri0*J1;
        dm0 = Ii[0]*c0 + Ii[1]*c1 + Ii[2]*c2;
        dm1 = Ii[3]*c0 + Ii[4]*c1 + Ii[5]*c2;
        dm2 = Ii[6]*c0 + Ii[7]*c1 + Ii[8]*c2;
      }
      v0 = v0*ldv + dv0;
      v1 = (v1 + GYDT)*ldv + dv1;
      v2 = v2*ldv + dv2;
      om0 = om0*adv + dm0; om1 = om1*adv + dm1; om2 = om2*adv + dm2;
      tr0 = tr0 + DTF*v0; tr1 = tr1 + DTF*v1; tr2 = tr2 + DTF*v2;
      float wx = om0*HDT, wy = om1*HDT, wz = om2*HDT;
      float dq0 = -wx*q1 - wy*q2 - wz*q3;
      float dq1 =  wx*q0 + wy*q3 - wz*q2;
      float dq2 =  wy*q0 + wz*q1 - wx*q3;
      float dq3 =  wz*q0 + wx*q2 - wy*q1;
      q0 += dq0; q1 += dq1; q2 += dq2; q3 += dq3;
      float qn2 = sqrtf(q0*q0 + q1*q1 + q2*q2 + q3*q3);
      q0 /= qn2; q1 /= qn2; q2 /= qn2; q3 /= qn2;
      if (bid == 0) {
        float* o = out + (size_t)t * 7;
        o[0] = tr0; o[1] = tr1; o[2] = tr2;
        o[3] = q0;  o[4] = q1;  o[5] = q2;  o[6] = q3;
      }
    }
  }
}

extern "C" void kernel_launch(void* const* d_in, const int* in_sizes, int n_in,
                              void* d_out, int out_size, void* d_ws, size_t ws_size,
                              hipStream_t stream) {
  const float* x   = (const float*)d_in[0];
  const float* mc  = (const float*)d_in[1];
  const float* itr = (const float*)d_in[2];
  const float* iq  = (const float*)d_in[3];
  const float* iv  = (const float*)d_in[4];
  const float* kn  = (const float*)d_in[5];
  const float* mu  = (const float*)d_in[6];
  const float* ldp = (const float*)d_in[7];
  const float* adp = (const float*)d_in[8];
  float* out = (float*)d_out;
  float* ws  = (float*)d_ws;
  int N = in_sizes[0] / 3;
  int T = out_size / 7;

  void* args[] = {(void*)&x, (void*)&mc, (void*)&itr, (void*)&iq, (void*)&iv,
                  (void*)&kn, (void*)&mu, (void*)&ldp, (void*)&adp,
                  (void*)&out, (void*)&ws, (void*)&N, (void*)&T};
  // cooperative launch kept ONLY for the co-residency guarantee (no grid.sync inside)
  hipLaunchCooperativeKernel((void*)sim_kernel, dim3(GRID), dim3(BLOCK),
                             args, 0, stream);
}

// Round 5
// 2391.046 us; speedup vs baseline: 3.3126x; 1.2743x over previous
//
#include <hip/hip_runtime.h>

#define GRID    256
#define BLOCK   512
#define NWAVES  (BLOCK / 64)
#define CHUNK   5340   // 3*CHUNK*4 = 64080 B LDS (+s_red/s_plane) < 64 KB

typedef unsigned long long u64;

// ---------------- fence-free tagged publish (cross-XCD safe) ----------------
// Relaxed agent-scope atomics on gfx950 emit global_load/store ... sc0 sc1:
// they bypass L1/L2 and hit the coherence point directly, with NO cache
// maintenance ops. Round 3 showed acquire polls (buffer_inv per poll) cost
// ~20 us/step; round 4 showed even one release fence per step (vmcnt drain +
// buffer_wbl2) leaves a ~10-poll-iteration visibility window. So: NO fences.
// Each 8B word = (f32 payload | tag<<32), stored with one atomic dwordx2.
// A word proves its own freshness; store order is irrelevant.
__device__ __forceinline__ u64 rec_load(const u64* p) {
  return __hip_atomic_load(p, __ATOMIC_RELAXED, __HIP_MEMORY_SCOPE_AGENT);
}
__device__ __forceinline__ void rec_store(u64* p, u64 v) {
  __hip_atomic_store(p, v, __ATOMIC_RELAXED, __HIP_MEMORY_SCOPE_AGENT);
}
__device__ __forceinline__ u64 rec_pack(float f, unsigned tag) {
  return (u64)__float_as_uint(f) | ((u64)tag << 32);
}

// ---------------- block reduction: NV values, result in thread 0 ----------------
template <int NV>
__device__ __forceinline__ void block_reduce(float* v, float* sm) {
  #pragma unroll
  for (int off = 32; off > 0; off >>= 1) {
    #pragma unroll
    for (int k = 0; k < NV; ++k) v[k] += __shfl_down(v[k], off, 64);
  }
  const int lane = threadIdx.x & 63;
  const int wid  = threadIdx.x >> 6;
  if (lane == 0) {
    #pragma unroll
    for (int k = 0; k < NV; ++k) sm[wid * NV + k] = v[k];
  }
  __syncthreads();
  if (threadIdx.x == 0) {
    #pragma unroll
    for (int w = 1; w < NWAVES; ++w) {
      #pragma unroll
      for (int k = 0; k < NV; ++k) v[k] += sm[w * NV + k];
    }
  }
  __syncthreads();
}

// ---------------- 3x3 helpers (row-major float[9]) ----------------
__device__ __forceinline__ void mat3_mul(const float* A, const float* B, float* C) {
  #pragma unroll
  for (int i = 0; i < 3; ++i)
    #pragma unroll
    for (int j = 0; j < 3; ++j)
      C[i*3+j] = A[i*3+0]*B[0*3+j] + A[i*3+1]*B[1*3+j] + A[i*3+2]*B[2*3+j];
}
__device__ __forceinline__ void mat3_mul_bt(const float* A, const float* B, float* C) {
  // C = A * B^T
  #pragma unroll
  for (int i = 0; i < 3; ++i)
    #pragma unroll
    for (int j = 0; j < 3; ++j)
      C[i*3+j] = A[i*3+0]*B[j*3+0] + A[i*3+1]*B[j*3+1] + A[i*3+2]*B[j*3+2];
}
__device__ __forceinline__ void mat3_inv(const float* m, float* inv) {
  float A =  (m[4]*m[8] - m[5]*m[7]);
  float B = -(m[3]*m[8] - m[5]*m[6]);
  float C =  (m[3]*m[7] - m[4]*m[6]);
  float det = m[0]*A + m[1]*B + m[2]*C;
  float id = 1.0f / det;
  inv[0] = A * id;
  inv[1] = -(m[1]*m[8] - m[2]*m[7]) * id;
  inv[2] =  (m[1]*m[5] - m[2]*m[4]) * id;
  inv[3] = B * id;
  inv[4] =  (m[0]*m[8] - m[2]*m[6]) * id;
  inv[5] = -(m[0]*m[5] - m[2]*m[3]) * id;
  inv[6] = C * id;
  inv[7] = -(m[0]*m[7] - m[1]*m[6]) * id;
  inv[8] =  (m[0]*m[4] - m[1]*m[3]) * id;
}

__global__ __launch_bounds__(BLOCK)
void sim_kernel(const float* __restrict__ xg,
                const float* __restrict__ mc_p,
                const float* __restrict__ itr_p,
                const float* __restrict__ iq_p,
                const float* __restrict__ iv_p,
                const float* __restrict__ kn_p,
                const float* __restrict__ mu_p,
                const float* __restrict__ ldp_p,
                const float* __restrict__ adp_p,
                float* __restrict__ out,
                u64* __restrict__ ws,
                int N, int T)
{
  const int tid = threadIdx.x;
  const int bid = blockIdx.x;
  const int gtid = bid * BLOCK + tid;
  const int gthreads = GRID * BLOCK;

  __shared__ __align__(16) float sXx[CHUNK];
  __shared__ __align__(16) float sXy[CHUNK];
  __shared__ __align__(16) float sXz[CHUNK];
  __shared__ float s_red[NWAVES * 8];
  __shared__ float s_plane[8];

  // fp32 constants exactly as the fp32 reference sees them
  const float nx  = (float)(-0.3420201433256687);   // -sin(20deg)
  const float ny  = (float)( 0.9396926207859084);   //  cos(20deg)
  const float DTF = (float)(1.0 / 60.0 / 10.0);
  const float HDT = (float)(0.5 * (1.0 / 60.0 / 10.0));
  const float DTH = (float)(-0.9396926207859084 * 0.1); // -COS_S*INIT_HEIGHT
  const float GYDT = -9.8f * (float)(1.0 / 60.0 / 10.0);

  const float mc0 = mc_p[0], mc1 = mc_p[1], mc2 = mc_p[2];

  // workspace: per-block 64B records (8 u64), no false sharing.
  // Poison 0xAAAAAAAA (high word) never equals any tag (1..241, 0xC0FFEE).
  u64* buf0 = ws;                  // GRID*8 u64
  u64* buf1 = ws + GRID * 8;       // GRID*8
  u64* bufI = ws + 2 * GRID * 8;   // GRID*8 : words 0..5 = inertia

  // ---- stage part of x into LDS (SoA) ----
  const int vstart = bid * CHUNK;
  int cl = N - vstart; if (cl > CHUNK) cl = CHUNK; if (cl < 0) cl = 0;
  for (int i = tid; i < cl; i += BLOCK) {
    const float* p = xg + (size_t)(vstart + i) * 3;
    sXx[i] = p[0]; sXy[i] = p[1]; sXz[i] = p[2];
  }
  __syncthreads();

  const int tailbase = GRID * CHUNK;   // verts beyond LDS capacity, stay in per-XCD L2

  // ---- inertia: S[i][j] = sum r_i r_j ----
  {
    float v6[6] = {0,0,0,0,0,0};
    for (int i = tid; i < cl; i += BLOCK) {
      float r0 = sXx[i] - mc0, r1 = sXy[i] - mc1, r2 = sXz[i] - mc2;
      v6[0] += r0*r0; v6[1] += r1*r1; v6[2] += r2*r2;
      v6[3] += r0*r1; v6[4] += r0*r2; v6[5] += r1*r2;
    }
    for (int i = tailbase + gtid; i < N; i += gthreads) {
      const float* p = xg + (size_t)i * 3;
      float r0 = p[0] - mc0, r1 = p[1] - mc1, r2 = p[2] - mc2;
      v6[0] += r0*r0; v6[1] += r1*r1; v6[2] += r2*r2;
      v6[3] += r0*r1; v6[4] += r0*r2; v6[5] += r1*r2;
    }
    block_reduce<6>(v6, s_red);
    if (tid == 0) {
      u64* rp = bufI + bid * 8;
      #pragma unroll
      for (int k = 0; k < 6; ++k) rec_store(rp + k, rec_pack(v6[k], 0xC0FFEEu));
    }
  }

  // all-to-all gather of inertia partials (tag-checked, fence-free)
  float In[9];
  {
    float v6[6] = {0,0,0,0,0,0};
    if (tid < GRID) {
      const u64* rp = bufI + tid * 8;
      u64 r[6];
      for (;;) {
        #pragma unroll
        for (int k = 0; k < 6; ++k) r[k] = rec_load(rp + k);
        bool ok = true;
        #pragma unroll
        for (int k = 0; k < 6; ++k) ok &= ((unsigned)(r[k] >> 32) == 0xC0FFEEu);
        if (ok) break;
        __builtin_amdgcn_s_sleep(1);
      }
      #pragma unroll
      for (int k = 0; k < 6; ++k) v6[k] = __uint_as_float((unsigned)r[k]);
    }
    block_reduce<6>(v6, s_red);
    // only thread 0's values are meaningful below
    float trc = v6[0] + v6[1] + v6[2];
    In[0] = trc - v6[0]; In[4] = trc - v6[1]; In[8] = trc - v6[2];
    In[1] = -v6[3]; In[3] = -v6[3];
    In[2] = -v6[4]; In[6] = -v6[4];
    In[5] = -v6[5]; In[7] = -v6[5];
  }

  // ---- initial state (thread-0-owned) ----
  float tr0 = itr_p[0], tr1 = itr_p[1], tr2 = itr_p[2];
  float q0 = iq_p[0], q1 = iq_p[1], q2 = iq_p[2], q3 = iq_p[3];
  {
    float n0 = sqrtf(q0*q0 + q1*q1 + q2*q2 + q3*q3);
    q0 /= n0; q1 /= n0; q2 /= n0; q3 /= n0;
  }
  float v0 = iv_p[0], v1 = iv_p[1], v2 = iv_p[2];
  float om0 = 0.f, om1 = 0.f, om2 = 0.f;
  const float knv = kn_p[0], muv = mu_p[0], ldv = ldp_p[0], adv = adp_p[0];
  const float inv_mass = 1.0f / (float)N;

  float Rm[9];

  for (int t = 0; t < T; ++t) {
    // ---- plane parameters from current state (thread 0) ----
    if (tid == 0) {
      float qn = sqrtf(q0*q0 + q1*q1 + q2*q2 + q3*q3);
      float w = q0/qn, xq = q1/qn, yq = q2/qn, zq = q3/qn;
      Rm[0] = 1.f - 2.f*yq*yq - 2.f*zq*zq; Rm[1] = 2.f*xq*yq - 2.f*w*zq; Rm[2] = 2.f*xq*zq + 2.f*w*yq;
      Rm[3] = 2.f*xq*yq + 2.f*w*zq; Rm[4] = 1.f - 2.f*xq*xq - 2.f*zq*zq; Rm[5] = 2.f*yq*zq - 2.f*w*xq;
      Rm[6] = 2.f*xq*zq - 2.f*w*yq; Rm[7] = 2.f*yq*zq + 2.f*w*xq; Rm[8] = 1.f - 2.f*xq*xq - 2.f*yq*yq;
      // a = R^T n
      float a0 = Rm[0]*nx + Rm[3]*ny;
      float a1 = Rm[1]*nx + Rm[4]*ny;
      float a2 = Rm[2]*nx + Rm[5]*ny;
      // w_ = n x omega ; b = R^T w_
      float w0 = ny*om2, w1 = -nx*om2, w2 = nx*om1 - ny*om0;
      float b0 = Rm[0]*w0 + Rm[3]*w1 + Rm[6]*w2;
      float b1 = Rm[1]*w0 + Rm[4]*w1 + Rm[7]*w2;
      float b2 = Rm[2]*w0 + Rm[5]*w1 + Rm[8]*w2;
      float ca = DTH - ((tr0 + mc0)*nx + (tr1 + mc1)*ny);
      float cb = -(v0*nx + v1*ny);
      s_plane[0] = a0; s_plane[1] = a1; s_plane[2] = a2;
      s_plane[3] = b0; s_plane[4] = b1; s_plane[5] = b2;
      s_plane[6] = ca; s_plane[7] = cb;
    }
    __syncthreads();
    const float a0 = s_plane[0], a1 = s_plane[1], a2 = s_plane[2];
    const float b0 = s_plane[3], b1 = s_plane[4], b2 = s_plane[5];
    const float ca = s_plane[6], cb = s_plane[7];

    // ---- masked reduction: LDS chunk + L2-resident tail ----
    float acc[4] = {0.f, 0.f, 0.f, 0.f};
    for (int i = tid; i < cl; i += BLOCK) {
      float x0 = sXx[i], x1 = sXy[i], x2 = sXz[i];
      float da = x0*a0 + x1*a1 + x2*a2;
      float db = x0*b0 + x1*b1 + x2*b2;
      if (da < ca && db < cb) { acc[0] += 1.f; acc[1] += x0; acc[2] += x1; acc[3] += x2; }
    }
    for (int i = tailbase + gtid; i < N; i += gthreads) {
      const float* p = xg + (size_t)i * 3;
      float x0 = p[0], x1 = p[1], x2 = p[2];
      float da = x0*a0 + x1*a1 + x2*a2;
      float db = x0*b0 + x1*b1 + x2*b2;
      if (da < ca && db < cb) { acc[0] += 1.f; acc[1] += x0; acc[2] += x1; acc[3] += x2; }
    }
    block_reduce<4>(acc, s_red);

    // ---- publish partial: 4 tagged 8B atomic stores, NO fence ----
    const unsigned want = (unsigned)(t + 1);
    u64* pb = (t & 1) ? buf1 : buf0;   // distance-2 reuse is WAR-safe: a block
                                       // overwrites buf[t&1] at t+2 only after
                                       // observing every block's t+1 publish,
                                       // which follows their step-t reads.
    if (tid == 0) {
      u64* rp = pb + bid * 8;
      #pragma unroll
      for (int k = 0; k < 4; ++k) rec_store(rp + k, rec_pack(acc[k], want));
    }

    // ---- all-to-all gather: thread j polls block j's tagged record ----
    float tot[4] = {0.f, 0.f, 0.f, 0.f};
    if (tid < GRID) {
      const u64* rp = pb + tid * 8;
      u64 r0, r1, r2, r3;
      for (;;) {
        r0 = rec_load(rp + 0); r1 = rec_load(rp + 1);
        r2 = rec_load(rp + 2); r3 = rec_load(rp + 3);
        if ((unsigned)(r0 >> 32) == want && (unsigned)(r1 >> 32) == want &&
            (unsigned)(r2 >> 32) == want && (unsigned)(r3 >> 32) == want) break;
        __builtin_amdgcn_s_sleep(1);
      }
      tot[0] = __uint_as_float((unsigned)r0);
      tot[1] = __uint_as_float((unsigned)r1);
      tot[2] = __uint_as_float((unsigned)r2);
      tot[3] = __uint_as_float((unsigned)r3);
    }
    block_reduce<4>(tot, s_red);

    // ---- serial physics update (thread 0 of every block, bit-identical) ----
    if (tid == 0) {
      float num = tot[0];
      float numf = fmaxf(num, 1.0f);
      float ri0 = tot[1] / numf, ri1 = tot[2] / numf, ri2 = tot[3] / numf;
      float Ri0 = Rm[0]*ri0 + Rm[1]*ri1 + Rm[2]*ri2;
      float Ri1 = Rm[3]*ri0 + Rm[4]*ri1 + Rm[5]*ri2;
      float Ri2 = Rm[6]*ri0 + Rm[7]*ri1 + Rm[8]*ri2;
      float dv0 = 0.f, dv1 = 0.f, dv2 = 0.f, dm0 = 0.f, dm1 = 0.f, dm2 = 0.f;
      if (num > 0.0f) {
        float vi0 = v0 + om1*Ri2 - om2*Ri1;
        float vi1 = v1 + om2*Ri0 - om0*Ri2;
        float vi2 = v2 + om0*Ri1 - om1*Ri0;
        float vdn = vi0*nx + vi1*ny;
        float vn0 = vdn*nx, vn1 = vdn*ny;           // vn2 == 0 exactly
        float vt0 = vi0 - vn0, vt1 = vi1 - vn1, vt2 = vi2;
        float nvn = sqrtf(vn0*vn0 + vn1*vn1);
        float nvt = sqrtf(vt0*vt0 + vt1*vt1 + vt2*vt2);
        float alpha = fmaxf(1.0f - muv*(1.0f + knv)*(nvn/(nvt + 1e-6f)), 0.0f);
        float dvi0 = (-knv*vn0 + alpha*vt0) - vi0;
        float dvi1 = (-knv*vn1 + alpha*vt1) - vi1;
        float dvi2 = (alpha*vt2) - vi2;
        float Tm[9]; mat3_mul(Rm, In, Tm);
        float Iw[9]; mat3_mul_bt(Tm, Rm, Iw);       // I = R * inertia * R^T
        float Ii[9]; mat3_inv(Iw, Ii);
        float Cx[9] = {0.f, -Ri2, Ri1,  Ri2, 0.f, -Ri0,  -Ri1, Ri0, 0.f};
        float T2[9]; mat3_mul(Cx, Ii, T2);
        float T3[9]; mat3_mul(T2, Cx, T3);
        float K[9];
        #pragma unroll
        for (int k = 0; k < 9; ++k) K[k] = -T3[k];
        K[0] += inv_mass; K[4] += inv_mass; K[8] += inv_mass;
        float Ki[9]; mat3_inv(K, Ki);
        float J0 = Ki[0]*dvi0 + Ki[1]*dvi1 + Ki[2]*dvi2;
        float J1 = Ki[3]*dvi0 + Ki[4]*dvi1 + Ki[5]*dvi2;
        float J2 = Ki[6]*dvi0 + Ki[7]*dvi1 + Ki[8]*dvi2;
        dv0 = J0*inv_mass; dv1 = J1*inv_mass; dv2 = J2*inv_mass;
        float c0 = -Ri2*J1 + Ri1*J2;
        float c1 =  Ri2*J0 - Ri0*J2;
        float c2 = -Ri1*J0 + Ri0*J1;
        dm0 = Ii[0]*c0 + Ii[1]*c1 + Ii[2]*c2;
        dm1 = Ii[3]*c0 + Ii[4]*c1 + Ii[5]*c2;
        dm2 = Ii[6]*c0 + Ii[7]*c1 + Ii[8]*c2;
      }
      v0 = v0*ldv + dv0;
      v1 = (v1 + GYDT)*ldv + dv1;
      v2 = v2*ldv + dv2;
      om0 = om0*adv + dm0; om1 = om1*adv + dm1; om2 = om2*adv + dm2;
      tr0 = tr0 + DTF*v0; tr1 = tr1 + DTF*v1; tr2 = tr2 + DTF*v2;
      float wx = om0*HDT, wy = om1*HDT, wz = om2*HDT;
      float dq0 = -wx*q1 - wy*q2 - wz*q3;
      float dq1 =  wx*q0 + wy*q3 - wz*q2;
      float dq2 =  wy*q0 + wz*q1 - wx*q3;
      float dq3 =  wz*q0 + wx*q2 - wy*q1;
      q0 += dq0; q1 += dq1; q2 += dq2; q3 += dq3;
      float qn2 = sqrtf(q0*q0 + q1*q1 + q2*q2 + q3*q3);
      q0 /= qn2; q1 /= qn2; q2 /= qn2; q3 /= qn2;
      if (bid == 0) {
        float* o = out + (size_t)t * 7;
        o[0] = tr0; o[1] = tr1; o[2] = tr2;
        o[3] = q0;  o[4] = q1;  o[5] = q2;  o[6] = q3;
      }
    }
  }
}

extern "C" void kernel_launch(void* const* d_in, const int* in_sizes, int n_in,
                              void* d_out, int out_size, void* d_ws, size_t ws_size,
                              hipStream_t stream) {
  const float* x   = (const float*)d_in[0];
  const float* mc  = (const float*)d_in[1];
  const float* itr = (const float*)d_in[2];
  const float* iq  = (const float*)d_in[3];
  const float* iv  = (const float*)d_in[4];
  const float* kn  = (const float*)d_in[5];
  const float* mu  = (const float*)d_in[6];
  const float* ldp = (const float*)d_in[7];
  const float* adp = (const float*)d_in[8];
  float* out = (float*)d_out;
  u64* ws  = (u64*)d_ws;
  int N = in_sizes[0] / 3;
  int T = out_size / 7;

  void* args[] = {(void*)&x, (void*)&mc, (void*)&itr, (void*)&iq, (void*)&iv,
                  (void*)&kn, (void*)&mu, (void*)&ldp, (void*)&adp,
                  (void*)&out, (void*)&ws, (void*)&N, (void*)&T};
  // cooperative launch kept ONLY for the co-residency guarantee (no grid.sync inside)
  hipLaunchCooperativeKernel((void*)sim_kernel, dim3(GRID), dim3(BLOCK),
                             args, 0, stream);
}

// Round 6
// 2098.132 us; speedup vs baseline: 3.7750x; 1.1396x over previous
//
#include <hip/hip_runtime.h>

#define GRID    256
#define BLOCK   512
#define NWAVES  (BLOCK / 64)
#define CHUNK   5340   // 3*CHUNK*4 = 64080 B LDS (+s_red/s_plane) < 64 KB

typedef unsigned long long u64;

// ---------------- fence-free tagged publish (cross-XCD safe) ----------------
// Relaxed agent-scope atomics on gfx950 emit global_load/store ... sc0 sc1:
// bypass L1/L2, hit the coherence point, NO cache maintenance ops.
// History: acquire polls (buffer_inv each) cost ~20us/step (r3); one release
// fence per step (vmcnt drain + wbl2) left a ~10-iteration visibility window
// (r4); tagged fence-free words got 9.7us/step (r5). r5's residual: thread j
// polled 64B record j -> each wave hit 64 scattered lines per iteration.
// This version: component-major SoA so each wave load covers 64 consecutive
// u64 (8 lines, coalesced). Each 8B word = (f32 payload | tag<<32); a word
// proves its own freshness, store order irrelevant, zero fences.
__device__ __forceinline__ u64 rec_load(const u64* p) {
  return __hip_atomic_load(p, __ATOMIC_RELAXED, __HIP_MEMORY_SCOPE_AGENT);
}
__device__ __forceinline__ void rec_store(u64* p, u64 v) {
  __hip_atomic_store(p, v, __ATOMIC_RELAXED, __HIP_MEMORY_SCOPE_AGENT);
}
__device__ __forceinline__ u64 rec_pack(float f, unsigned tag) {
  return (u64)__float_as_uint(f) | ((u64)tag << 32);
}

// ---------------- block reduction: NV values, result in thread 0 ----------------
template <int NV>
__device__ __forceinline__ void block_reduce(float* v, float* sm) {
  #pragma unroll
  for (int off = 32; off > 0; off >>= 1) {
    #pragma unroll
    for (int k = 0; k < NV; ++k) v[k] += __shfl_down(v[k], off, 64);
  }
  const int lane = threadIdx.x & 63;
  const int wid  = threadIdx.x >> 6;
  if (lane == 0) {
    #pragma unroll
    for (int k = 0; k < NV; ++k) sm[wid * NV + k] = v[k];
  }
  __syncthreads();
  if (threadIdx.x == 0) {
    #pragma unroll
    for (int w = 1; w < NWAVES; ++w) {
      #pragma unroll
      for (int k = 0; k < NV; ++k) v[k] += sm[w * NV + k];
    }
  }
  __syncthreads();
}

// ---------------- 3x3 helpers (row-major float[9]) ----------------
__device__ __forceinline__ void mat3_mul(const float* A, const float* B, float* C) {
  #pragma unroll
  for (int i = 0; i < 3; ++i)
    #pragma unroll
    for (int j = 0; j < 3; ++j)
      C[i*3+j] = A[i*3+0]*B[0*3+j] + A[i*3+1]*B[1*3+j] + A[i*3+2]*B[2*3+j];
}
__device__ __forceinline__ void mat3_mul_bt(const float* A, const float* B, float* C) {
  // C = A * B^T
  #pragma unroll
  for (int i = 0; i < 3; ++i)
    #pragma unroll
    for (int j = 0; j < 3; ++j)
      C[i*3+j] = A[i*3+0]*B[j*3+0] + A[i*3+1]*B[j*3+1] + A[i*3+2]*B[j*3+2];
}
__device__ __forceinline__ void mat3_inv(const float* m, float* inv) {
  float A =  (m[4]*m[8] - m[5]*m[7]);
  float B = -(m[3]*m[8] - m[5]*m[6]);
  float C =  (m[3]*m[7] - m[4]*m[6]);
  float det = m[0]*A + m[1]*B + m[2]*C;
  float id = 1.0f / det;
  inv[0] = A * id;
  inv[1] = -(m[1]*m[8] - m[2]*m[7]) * id;
  inv[2] =  (m[1]*m[5] - m[2]*m[4]) * id;
  inv[3] = B * id;
  inv[4] =  (m[0]*m[8] - m[2]*m[6]) * id;
  inv[5] = -(m[0]*m[5] - m[2]*m[3]) * id;
  inv[6] = C * id;
  inv[7] = -(m[0]*m[7] - m[1]*m[6]) * id;
  inv[8] =  (m[0]*m[4] - m[1]*m[3]) * id;
}

__global__ __launch_bounds__(BLOCK)
void sim_kernel(const float* __restrict__ xg,
                const float* __restrict__ mc_p,
                const float* __restrict__ itr_p,
                const float* __restrict__ iq_p,
                const float* __restrict__ iv_p,
                const float* __restrict__ kn_p,
                const float* __restrict__ mu_p,
                const float* __restrict__ ldp_p,
                const float* __restrict__ adp_p,
                float* __restrict__ out,
                u64* __restrict__ ws,
                int N, int T)
{
  const int tid = threadIdx.x;
  const int bid = blockIdx.x;
  const int gtid = bid * BLOCK + tid;
  const int gthreads = GRID * BLOCK;

  __shared__ __align__(16) float sXx[CHUNK];
  __shared__ __align__(16) float sXy[CHUNK];
  __shared__ __align__(16) float sXz[CHUNK];
  __shared__ float s_red[NWAVES * 8];
  __shared__ float s_plane[8];

  // fp32 constants exactly as the fp32 reference sees them
  const float nx  = (float)(-0.3420201433256687);   // -sin(20deg)
  const float ny  = (float)( 0.9396926207859084);   //  cos(20deg)
  const float DTF = (float)(1.0 / 60.0 / 10.0);
  const float HDT = (float)(0.5 * (1.0 / 60.0 / 10.0));
  const float DTH = (float)(-0.9396926207859084 * 0.1); // -COS_S*INIT_HEIGHT
  const float GYDT = -9.8f * (float)(1.0 / 60.0 / 10.0);

  const float mc0 = mc_p[0], mc1 = mc_p[1], mc2 = mc_p[2];

  // workspace, component-major (SoA): comp k of block j at buf[k*GRID + j].
  // Poison 0xAAAAAAAA (high word) never equals any tag (1..241, 0xC0FFEE).
  u64* buf0 = ws;                  // 4*GRID u64 (even steps)
  u64* buf1 = ws + 4 * GRID;       // 4*GRID (odd steps)
  u64* bufI = ws + 8 * GRID;       // 6*GRID (inertia)

  // ---- stage part of x into LDS (SoA) ----
  const int vstart = bid * CHUNK;
  int cl = N - vstart; if (cl > CHUNK) cl = CHUNK; if (cl < 0) cl = 0;
  for (int i = tid; i < cl; i += BLOCK) {
    const float* p = xg + (size_t)(vstart + i) * 3;
    sXx[i] = p[0]; sXy[i] = p[1]; sXz[i] = p[2];
  }
  __syncthreads();

  const int tailbase = GRID * CHUNK;   // verts beyond LDS capacity, stay in per-XCD L2

  // ---- inertia: S[i][j] = sum r_i r_j ----
  {
    float v6[6] = {0,0,0,0,0,0};
    for (int i = tid; i < cl; i += BLOCK) {
      float r0 = sXx[i] - mc0, r1 = sXy[i] - mc1, r2 = sXz[i] - mc2;
      v6[0] += r0*r0; v6[1] += r1*r1; v6[2] += r2*r2;
      v6[3] += r0*r1; v6[4] += r0*r2; v6[5] += r1*r2;
    }
    for (int i = tailbase + gtid; i < N; i += gthreads) {
      const float* p = xg + (size_t)i * 3;
      float r0 = p[0] - mc0, r1 = p[1] - mc1, r2 = p[2] - mc2;
      v6[0] += r0*r0; v6[1] += r1*r1; v6[2] += r2*r2;
      v6[3] += r0*r1; v6[4] += r0*r2; v6[5] += r1*r2;
    }
    block_reduce<6>(v6, s_red);
    if (tid == 0) {
      #pragma unroll
      for (int k = 0; k < 6; ++k) rec_store(bufI + k * GRID + bid, rec_pack(v6[k], 0xC0FFEEu));
    }
  }

  // all-to-all gather of inertia partials (SoA coalesced, tag-checked, fence-free)
  float In[9];
  {
    float v6[6] = {0,0,0,0,0,0};
    if (tid < GRID) {
      u64 r[6];
      int f = 0;
      for (;;) {
        #pragma unroll
        for (int k = 0; k < 6; ++k) r[k] = rec_load(bufI + k * GRID + tid);
        bool ok = true;
        #pragma unroll
        for (int k = 0; k < 6; ++k) ok &= ((unsigned)(r[k] >> 32) == 0xC0FFEEu);
        if (ok) break;
        if ((++f & 15) == 0) __builtin_amdgcn_s_sleep(1);
      }
      #pragma unroll
      for (int k = 0; k < 6; ++k) v6[k] = __uint_as_float((unsigned)r[k]);
    }
    block_reduce<6>(v6, s_red);
    // only thread 0's values are meaningful below
    float trc = v6[0] + v6[1] + v6[2];
    In[0] = trc - v6[0]; In[4] = trc - v6[1]; In[8] = trc - v6[2];
    In[1] = -v6[3]; In[3] = -v6[3];
    In[2] = -v6[4]; In[6] = -v6[4];
    In[5] = -v6[5]; In[7] = -v6[5];
  }

  // ---- initial state (thread-0-owned) ----
  float tr0 = itr_p[0], tr1 = itr_p[1], tr2 = itr_p[2];
  float q0 = iq_p[0], q1 = iq_p[1], q2 = iq_p[2], q3 = iq_p[3];
  {
    float n0 = sqrtf(q0*q0 + q1*q1 + q2*q2 + q3*q3);
    q0 /= n0; q1 /= n0; q2 /= n0; q3 /= n0;
  }
  float v0 = iv_p[0], v1 = iv_p[1], v2 = iv_p[2];
  float om0 = 0.f, om1 = 0.f, om2 = 0.f;
  const float knv = kn_p[0], muv = mu_p[0], ldv = ldp_p[0], adv = adp_p[0];
  const float inv_mass = 1.0f / (float)N;

  float Rm[9];

  for (int t = 0; t < T; ++t) {
    // ---- plane parameters from current state (thread 0) ----
    if (tid == 0) {
      float qn = sqrtf(q0*q0 + q1*q1 + q2*q2 + q3*q3);
      float w = q0/qn, xq = q1/qn, yq = q2/qn, zq = q3/qn;
      Rm[0] = 1.f - 2.f*yq*yq - 2.f*zq*zq; Rm[1] = 2.f*xq*yq - 2.f*w*zq; Rm[2] = 2.f*xq*zq + 2.f*w*yq;
      Rm[3] = 2.f*xq*yq + 2.f*w*zq; Rm[4] = 1.f - 2.f*xq*xq - 2.f*zq*zq; Rm[5] = 2.f*yq*zq - 2.f*w*xq;
      Rm[6] = 2.f*xq*zq - 2.f*w*yq; Rm[7] = 2.f*yq*zq + 2.f*w*xq; Rm[8] = 1.f - 2.f*xq*xq - 2.f*yq*yq;
      // a = R^T n
      float a0 = Rm[0]*nx + Rm[3]*ny;
      float a1 = Rm[1]*nx + Rm[4]*ny;
      float a2 = Rm[2]*nx + Rm[5]*ny;
      // w_ = n x omega ; b = R^T w_
      float w0 = ny*om2, w1 = -nx*om2, w2 = nx*om1 - ny*om0;
      float b0 = Rm[0]*w0 + Rm[3]*w1 + Rm[6]*w2;
      float b1 = Rm[1]*w0 + Rm[4]*w1 + Rm[7]*w2;
      float b2 = Rm[2]*w0 + Rm[5]*w1 + Rm[8]*w2;
      float ca = DTH - ((tr0 + mc0)*nx + (tr1 + mc1)*ny);
      float cb = -(v0*nx + v1*ny);
      s_plane[0] = a0; s_plane[1] = a1; s_plane[2] = a2;
      s_plane[3] = b0; s_plane[4] = b1; s_plane[5] = b2;
      s_plane[6] = ca; s_plane[7] = cb;
    }
    __syncthreads();
    const float a0 = s_plane[0], a1 = s_plane[1], a2 = s_plane[2];
    const float b0 = s_plane[3], b1 = s_plane[4], b2 = s_plane[5];
    const float ca = s_plane[6], cb = s_plane[7];

    // ---- masked reduction: LDS chunk + L2-resident tail ----
    float acc[4] = {0.f, 0.f, 0.f, 0.f};
    for (int i = tid; i < cl; i += BLOCK) {
      float x0 = sXx[i], x1 = sXy[i], x2 = sXz[i];
      float da = x0*a0 + x1*a1 + x2*a2;
      float db = x0*b0 + x1*b1 + x2*b2;
      if (da < ca && db < cb) { acc[0] += 1.f; acc[1] += x0; acc[2] += x1; acc[3] += x2; }
    }
    for (int i = tailbase + gtid; i < N; i += gthreads) {
      const float* p = xg + (size_t)i * 3;
      float x0 = p[0], x1 = p[1], x2 = p[2];
      float da = x0*a0 + x1*a1 + x2*a2;
      float db = x0*b0 + x1*b1 + x2*b2;
      if (da < ca && db < cb) { acc[0] += 1.f; acc[1] += x0; acc[2] += x1; acc[3] += x2; }
    }
    block_reduce<4>(acc, s_red);

    // ---- publish partial: 4 tagged 8B atomic stores (SoA), NO fence ----
    const unsigned want = (unsigned)(t + 1);
    u64* pb = (t & 1) ? buf1 : buf0;   // distance-2 reuse is WAR-safe: a block
                                       // overwrites buf[t&1] at t+2 only after
                                       // observing every block's t+1 publish,
                                       // which follows their step-t reads.
    if (tid == 0) {
      #pragma unroll
      for (int k = 0; k < 4; ++k) rec_store(pb + k * GRID + bid, rec_pack(acc[k], want));
    }

    // ---- all-to-all gather: thread j polls component-major words of block j.
    // Lane l of wave w loads pb[k*GRID + 64w + l]: 64 consecutive u64 = 8
    // lines per instruction (coalesced), 32 lines per block-iteration total.
    float tot[4] = {0.f, 0.f, 0.f, 0.f};
    if (tid < GRID) {
      u64 r0, r1, r2, r3;
      int f = 0;
      for (;;) {
        r0 = rec_load(pb + 0 * GRID + tid);
        r1 = rec_load(pb + 1 * GRID + tid);
        r2 = rec_load(pb + 2 * GRID + tid);
        r3 = rec_load(pb + 3 * GRID + tid);
        if ((unsigned)(r0 >> 32) == want && (unsigned)(r1 >> 32) == want &&
            (unsigned)(r2 >> 32) == want && (unsigned)(r3 >> 32) == want) break;
        if ((++f & 15) == 0) __builtin_amdgcn_s_sleep(1);
      }
      tot[0] = __uint_as_float((unsigned)r0);
      tot[1] = __uint_as_float((unsigned)r1);
      tot[2] = __uint_as_float((unsigned)r2);
      tot[3] = __uint_as_float((unsigned)r3);
    }
    block_reduce<4>(tot, s_red);

    // ---- serial physics update (thread 0 of every block, bit-identical) ----
    if (tid == 0) {
      float num = tot[0];
      float numf = fmaxf(num, 1.0f);
      float ri0 = tot[1] / numf, ri1 = tot[2] / numf, ri2 = tot[3] / numf;
      float Ri0 = Rm[0]*ri0 + Rm[1]*ri1 + Rm[2]*ri2;
      float Ri1 = Rm[3]*ri0 + Rm[4]*ri1 + Rm[5]*ri2;
      float Ri2 = Rm[6]*ri0 + Rm[7]*ri1 + Rm[8]*ri2;
      float dv0 = 0.f, dv1 = 0.f, dv2 = 0.f, dm0 = 0.f, dm1 = 0.f, dm2 = 0.f;
      if (num > 0.0f) {
        float vi0 = v0 + om1*Ri2 - om2*Ri1;
        float vi1 = v1 + om2*Ri0 - om0*Ri2;
        float vi2 = v2 + om0*Ri1 - om1*Ri0;
        float vdn = vi0*nx + vi1*ny;
        float vn0 = vdn*nx, vn1 = vdn*ny;           // vn2 == 0 exactly
        float vt0 = vi0 - vn0, vt1 = vi1 - vn1, vt2 = vi2;
        float nvn = sqrtf(vn0*vn0 + vn1*vn1);
        float nvt = sqrtf(vt0*vt0 + vt1*vt1 + vt2*vt2);
        float alpha = fmaxf(1.0f - muv*(1.0f + knv)*(nvn/(nvt + 1e-6f)), 0.0f);
        float dvi0 = (-knv*vn0 + alpha*vt0) - vi0;
        float dvi1 = (-knv*vn1 + alpha*vt1) - vi1;
        float dvi2 = (alpha*vt2) - vi2;
        float Tm[9]; mat3_mul(Rm, In, Tm);
        float Iw[9]; mat3_mul_bt(Tm, Rm, Iw);       // I = R * inertia * R^T
        float Ii[9]; mat3_inv(Iw, Ii);
        float Cx[9] = {0.f, -Ri2, Ri1,  Ri2, 0.f, -Ri0,  -Ri1, Ri0, 0.f};
        float T2[9]; mat3_mul(Cx, Ii, T2);
        float T3[9]; mat3_mul(T2, Cx, T3);
        float K[9];
        #pragma unroll
        for (int k = 0; k < 9; ++k) K[k] = -T3[k];
        K[0] += inv_mass; K[4] += inv_mass; K[8] += inv_mass;
        float Ki[9]; mat3_inv(K, Ki);
        float J0 = Ki[0]*dvi0 + Ki[1]*dvi1 + Ki[2]*dvi2;
        float J1 = Ki[3]*dvi0 + Ki[4]*dvi1 + Ki[5]*dvi2;
        float J2 = Ki[6]*dvi0 + Ki[7]*dvi1 + Ki[8]*dvi2;
        dv0 = J0*inv_mass; dv1 = J1*inv_mass; dv2 = J2*inv_mass;
        float c0 = -Ri2*J1 + Ri1*J2;
        float c1 =  Ri2*J0 - Ri0*J2;
        float c2 = -Ri1*J0 + Ri0*J1;
        dm0 = Ii[0]*c0 + Ii[1]*c1 + Ii[2]*c2;
        dm1 = Ii[3]*c0 + Ii[4]*c1 + Ii[5]*c2;
        dm2 = Ii[6]*c0 + Ii[7]*c1 + Ii[8]*c2;
      }
      v0 = v0*ldv + dv0;
      v1 = (v1 + GYDT)*ldv + dv1;
      v2 = v2*ldv + dv2;
      om0 = om0*adv + dm0; om1 = om1*adv + dm1; om2 = om2*adv + dm2;
      tr0 = tr0 + DTF*v0; tr1 = tr1 + DTF*v1; tr2 = tr2 + DTF*v2;
      float wx = om0*HDT, wy = om1*HDT, wz = om2*HDT;
      float dq0 = -wx*q1 - wy*q2 - wz*q3;
      float dq1 =  wx*q0 + wy*q3 - wz*q2;
      float dq2 =  wy*q0 + wz*q1 - wx*q3;
      float dq3 =  wz*q0 + wx*q2 - wy*q1;
      q0 += dq0; q1 += dq1; q2 += dq2; q3 += dq3;
      float qn2 = sqrtf(q0*q0 + q1*q1 + q2*q2 + q3*q3);
      q0 /= qn2; q1 /= qn2; q2 /= qn2; q3 /= qn2;
      if (bid == 0) {
        float* o = out + (size_t)t * 7;
        o[0] = tr0; o[1] = tr1; o[2] = tr2;
        o[3] = q0;  o[4] = q1;  o[5] = q2;  o[6] = q3;
      }
    }
  }
}

extern "C" void kernel_launch(void* const* d_in, const int* in_sizes, int n_in,
                              void* d_out, int out_size, void* d_ws, size_t ws_size,
                              hipStream_t stream) {
  const float* x   = (const float*)d_in[0];
  const float* mc  = (const float*)d_in[1];
  const float* itr = (const float*)d_in[2];
  const float* iq  = (const float*)d_in[3];
  const float* iv  = (const float*)d_in[4];
  const float* kn  = (const float*)d_in[5];
  const float* mu  = (const float*)d_in[6];
  const float* ldp = (const float*)d_in[7];
  const float* adp = (const float*)d_in[8];
  float* out = (float*)d_out;
  u64* ws  = (u64*)d_ws;
  int N = in_sizes[0] / 3;
  int T = out_size / 7;

  void* args[] = {(void*)&x, (void*)&mc, (void*)&itr, (void*)&iq, (void*)&iv,
                  (void*)&kn, (void*)&mu, (void*)&ldp, (void*)&adp,
                  (void*)&out, (void*)&ws, (void*)&N, (void*)&T};
  // cooperative launch kept ONLY for the co-residency guarantee (no grid.sync inside)
  hipLaunchCooperativeKernel((void*)sim_kernel, dim3(GRID), dim3(BLOCK),
                             args, 0, stream);
}